// Round 1
// baseline (5701.877 us; speedup 1.0000x reference)
//
#include <hip/hip_runtime.h>

// Problem constants (fixed by the reference).
#define NUQ 100000
#define NIQ 200000
#define BBQ 3
#define EEQ 1000000
#define DDQ 64

__device__ __forceinline__ float sigmoidf_(float x) {
    return 1.0f / (1.0f + __expf(-x));
}

// COO scatter: for each edge e (flat over [B*E]): out[b, rows[e], :] += vals[e] * src[cols[e], :]
// 16 threads per edge, float4 per thread.
__global__ __launch_bounds__(256) void scatter_kernel(
    const float* __restrict__ vals,
    const int* __restrict__ rows,
    const int* __restrict__ cols,
    const float* __restrict__ src,     // [n_src, 64]
    float* __restrict__ out,           // [B, n_rows, 64]
    long long bstride)                 // n_rows * 64
{
    long long gid = (long long)blockIdx.x * 256 + threadIdx.x;
    long long edge = gid >> 4;
    int sub = ((int)gid & 15) << 2;    // d offset, multiple of 4
    float v = vals[edge];
    long long r = rows[edge];
    long long c = cols[edge];
    int b = (int)(edge / EEQ);
    const float4 s = *reinterpret_cast<const float4*>(src + c * DDQ + sub);
    float* o = out + (long long)b * bstride + r * DDQ + sub;
    atomicAdd(o + 0, v * s.x);
    atomicAdd(o + 1, v * s.y);
    atomicAdd(o + 2, v * s.z);
    atomicAdd(o + 3, v * s.w);
}

// In-place per-row GEMM + sigmoid over the 3 behavior accumulators, plus the
// mean-over-B path: out_mean[n] = sigmoid(mean_b(acc_b[n]) @ W).
// Block = 256 threads = 4 waves; wave r handles one row per chunk, lane j = output col.
__global__ __launch_bounds__(256) void dense_kernel(
    float* __restrict__ acc,        // [B, N, 64], in/out (in-place)
    const float* __restrict__ W,    // [64, 64] row-major, out[j] = sum_d row[d]*W[d*64+j]
    float* __restrict__ out_mean,   // [N, 64]
    int N, long long bstride)
{
    __shared__ float Wl[64 * 64];
    __shared__ float rowsl[4][3][64];
    int tid = threadIdx.x;
    #pragma unroll
    for (int i = tid; i < 64 * 64; i += 256) Wl[i] = W[i];
    int r = tid >> 6;
    int j = tid & 63;
    int row0 = blockIdx.x * 32;
    for (int chunk = 0; chunk < 32; chunk += 4) {
        int n = row0 + chunk + r;
        __syncthreads();   // protects rowsl reuse + (first iter) W load
        if (n < N) {
            #pragma unroll
            for (int b = 0; b < 3; b++)
                rowsl[r][b][j] = acc[(long long)b * bstride + (long long)n * DDQ + j];
        }
        __syncthreads();
        if (n < N) {
            float a0 = 0.f, a1 = 0.f, a2 = 0.f;
            const float4* r0 = reinterpret_cast<const float4*>(&rowsl[r][0][0]);
            const float4* r1 = reinterpret_cast<const float4*>(&rowsl[r][1][0]);
            const float4* r2 = reinterpret_cast<const float4*>(&rowsl[r][2][0]);
            #pragma unroll
            for (int dq = 0; dq < 16; dq++) {
                float4 v0 = r0[dq], v1 = r1[dq], v2 = r2[dq];
                int d = dq * 4;
                float w0 = Wl[(d + 0) * 64 + j];
                float w1 = Wl[(d + 1) * 64 + j];
                float w2 = Wl[(d + 2) * 64 + j];
                float w3 = Wl[(d + 3) * 64 + j];
                a0 += v0.x * w0 + v0.y * w1 + v0.z * w2 + v0.w * w3;
                a1 += v1.x * w0 + v1.y * w1 + v1.z * w2 + v1.w * w3;
                a2 += v2.x * w0 + v2.y * w1 + v2.z * w2 + v2.w * w3;
            }
            float am = (a0 + a1 + a2) * (1.0f / 3.0f);
            long long off = (long long)n * DDQ + j;
            acc[off] = sigmoidf_(a0);
            acc[bstride + off] = sigmoidf_(a1);
            acc[2 * bstride + off] = sigmoidf_(a2);
            out_mean[off] = sigmoidf_(am);
        }
    }
}

extern "C" void kernel_launch(void* const* d_in, const int* in_sizes, int n_in,
                              void* d_out, int out_size, void* d_ws, size_t ws_size,
                              hipStream_t stream) {
    const float* user_emb = (const float*)d_in[0];
    const float* item_emb = (const float*)d_in[1];
    const float* u2i_vals = (const float*)d_in[2];
    const int*   u2i_rows = (const int*)d_in[3];
    const int*   u2i_cols = (const int*)d_in[4];
    const float* i2u_vals = (const float*)d_in[5];
    const int*   i2u_rows = (const int*)d_in[6];
    const int*   i2u_cols = (const int*)d_in[7];
    const float* u_w = (const float*)d_in[8];
    const float* i_w = (const float*)d_in[9];

    float* out = (float*)d_out;
    // Output layout: ue [NU*64] | ie [NI*64] | ues [B*NU*64] | ies [B*NI*64]
    float* out_ue  = out;
    float* out_ie  = out + (long long)NUQ * DDQ;
    float* out_ues = out + (long long)(NUQ + NIQ) * DDQ;
    float* out_ies = out_ues + (long long)BBQ * NUQ * DDQ;

    // Zero the SpMM accumulator regions (ues/ies are accumulated in-place).
    hipMemsetAsync(out_ues, 0, (size_t)BBQ * (NUQ + NIQ) * DDQ * sizeof(float), stream);

    long long nthreads = (long long)BBQ * EEQ * 16;
    int nblocks = (int)(nthreads / 256);   // 187500, exact
    scatter_kernel<<<nblocks, 256, 0, stream>>>(u2i_vals, u2i_rows, u2i_cols,
                                                item_emb, out_ues,
                                                (long long)NUQ * DDQ);
    scatter_kernel<<<nblocks, 256, 0, stream>>>(i2u_vals, i2u_rows, i2u_cols,
                                                user_emb, out_ies,
                                                (long long)NIQ * DDQ);

    dense_kernel<<<NUQ / 32, 256, 0, stream>>>(out_ues, u_w, out_ue, NUQ,
                                               (long long)NUQ * DDQ);
    dense_kernel<<<NIQ / 32, 256, 0, stream>>>(out_ies, i_w, out_ie, NIQ,
                                               (long long)NIQ * DDQ);
}